// Round 1
// baseline (248.683 us; speedup 1.0000x reference)
//
#include <hip/hip_runtime.h>
#include <hip/hip_bf16.h>

// Problem constants
#define B    2
#define CIN  256
#define H    56
#define W    56
#define OUTC 256
#define KS   7
#define PAD  3
#define G    8
#define CG   32
#define HP   62           // H + 2*PAD
#define WP   62
#define P1   (H * W)      // 3136
#define P2   (HP * WP)    // 3844

// GEMM tile
#define TO 64
#define TP 64
#define TK 16

// ---------------------------------------------------------------------------
// q[b,o,p] = sum_c w_q[o,c] * fm[b, CIN + c, p]          (p over 3136, exact)
// ---------------------------------------------------------------------------
__global__ __launch_bounds__(256) void proj_q_kernel(const float* __restrict__ fm,
                                                     const float* __restrict__ wq,
                                                     float* __restrict__ q) {
    __shared__ float sW[TK][TO + 1];   // sW[k][o]
    __shared__ float sX[TK][TP];       // sX[k][p]
    const int b  = blockIdx.z;
    const int o0 = blockIdx.y * TO;
    const int p0 = blockIdx.x * TP;
    const float* X = fm + ((size_t)b * (2 * CIN) + CIN) * P1;   // fm_t1[b]
    const int tid = threadIdx.x;
    const int tx = tid & 15;     // p sub-index
    const int ty = tid >> 4;     // o sub-index

    float acc[4][4] = {};
    for (int k0 = 0; k0 < CIN; k0 += TK) {
        { // W tile: 64 o x 16 k
            const int k = tid & 15;
            const int o = tid >> 4;
            #pragma unroll
            for (int r = 0; r < 4; ++r)
                sW[k][o + 16 * r] = wq[(size_t)(o0 + o + 16 * r) * CIN + k0 + k];
        }
        { // X tile: 16 k x 64 p
            const int p  = tid & 63;
            const int kr = tid >> 6;          // 0..3
            #pragma unroll
            for (int r = 0; r < 4; ++r)
                sX[kr + 4 * r][p] = X[(size_t)(k0 + kr + 4 * r) * P1 + p0 + p];
        }
        __syncthreads();
        #pragma unroll
        for (int k = 0; k < TK; ++k) {
            float xs[4], wsr[4];
            #pragma unroll
            for (int bb = 0; bb < 4; ++bb) xs[bb] = sX[k][tx + 16 * bb];
            #pragma unroll
            for (int aa = 0; aa < 4; ++aa) wsr[aa] = sW[k][ty + 16 * aa];
            #pragma unroll
            for (int aa = 0; aa < 4; ++aa)
                #pragma unroll
                for (int bb = 0; bb < 4; ++bb)
                    acc[aa][bb] += wsr[aa] * xs[bb];
        }
        __syncthreads();
    }
    float* qb = q + (size_t)b * OUTC * P1;
    #pragma unroll
    for (int aa = 0; aa < 4; ++aa)
        #pragma unroll
        for (int bb = 0; bb < 4; ++bb)
            qb[(size_t)(o0 + ty + 16 * aa) * P1 + p0 + tx + 16 * bb] = acc[aa][bb];
}

// ---------------------------------------------------------------------------
// kk[b,o,pp] = sum_c w_k[o,c] * padded(fm_t0)[b,c,pp]   (pp over 62*62)
// vv        = same with w_v  (shares the X tile)
// ---------------------------------------------------------------------------
__global__ __launch_bounds__(256) void proj_kv_kernel(const float* __restrict__ fm,
                                                      const float* __restrict__ wk,
                                                      const float* __restrict__ wv,
                                                      float* __restrict__ kk,
                                                      float* __restrict__ vv) {
    __shared__ float sWk[TK][TO + 1];
    __shared__ float sWv[TK][TO + 1];
    __shared__ float sX[TK][TP];
    const int b  = blockIdx.z;
    const int o0 = blockIdx.y * TO;
    const int p0 = blockIdx.x * TP;
    const float* X = fm + (size_t)b * (2 * CIN) * P1;   // fm_t0[b]
    const int tid = threadIdx.x;
    const int tx = tid & 15;
    const int ty = tid >> 4;

    // Per-thread padded-pixel -> source offset for the X loader (fixed over k loop)
    const int pl = p0 + (tid & 63);
    int srcoff = -1;
    if (pl < P2) {
        const int y = pl / WP, x = pl - y * WP;
        const int iy = y - PAD, ix = x - PAD;
        if (iy >= 0 && iy < H && ix >= 0 && ix < W) srcoff = iy * W + ix;
    }

    float acck[4][4] = {};
    float accv[4][4] = {};
    for (int k0 = 0; k0 < CIN; k0 += TK) {
        {
            const int k = tid & 15;
            const int o = tid >> 4;
            #pragma unroll
            for (int r = 0; r < 4; ++r) {
                sWk[k][o + 16 * r] = wk[(size_t)(o0 + o + 16 * r) * CIN + k0 + k];
                sWv[k][o + 16 * r] = wv[(size_t)(o0 + o + 16 * r) * CIN + k0 + k];
            }
        }
        {
            const int p  = tid & 63;
            const int kr = tid >> 6;
            #pragma unroll
            for (int r = 0; r < 4; ++r) {
                float v = 0.f;
                if (srcoff >= 0) v = X[(size_t)(k0 + kr + 4 * r) * P1 + srcoff];
                sX[kr + 4 * r][p] = v;
            }
        }
        __syncthreads();
        #pragma unroll
        for (int k = 0; k < TK; ++k) {
            float xs[4], wks[4], wvs[4];
            #pragma unroll
            for (int bb = 0; bb < 4; ++bb) xs[bb] = sX[k][tx + 16 * bb];
            #pragma unroll
            for (int aa = 0; aa < 4; ++aa) { wks[aa] = sWk[k][ty + 16 * aa]; wvs[aa] = sWv[k][ty + 16 * aa]; }
            #pragma unroll
            for (int aa = 0; aa < 4; ++aa)
                #pragma unroll
                for (int bb = 0; bb < 4; ++bb) {
                    acck[aa][bb] += wks[aa] * xs[bb];
                    accv[aa][bb] += wvs[aa] * xs[bb];
                }
        }
        __syncthreads();
    }
    float* kb = kk + (size_t)b * OUTC * P2;
    float* vb = vv + (size_t)b * OUTC * P2;
    #pragma unroll
    for (int aa = 0; aa < 4; ++aa)
        #pragma unroll
        for (int bb = 0; bb < 4; ++bb) {
            const int p = p0 + tx + 16 * bb;
            if (p < P2) {
                kb[(size_t)(o0 + ty + 16 * aa) * P2 + p] = acck[aa][bb];
                vb[(size_t)(o0 + ty + 16 * aa) * P2 + p] = accv[aa][bb];
            }
        }
}

// ---------------------------------------------------------------------------
// Grouped 7x7 attention. One thread = one (b, g, pixel).
// logits[t=(i,j)] = sum_c q[c] * kk[c, h+i, w+j] + biasdot(i or j)
// ---------------------------------------------------------------------------
__global__ __launch_bounds__(256) void attn_kernel(const float* __restrict__ q,
                                                   const float* __restrict__ kk,
                                                   const float* __restrict__ vv,
                                                   const float* __restrict__ rel_h,
                                                   const float* __restrict__ rel_w,
                                                   float* __restrict__ out) {
    const int b = blockIdx.z;
    const int g = blockIdx.y;
    const int pix = blockIdx.x * 256 + threadIdx.x;
    if (pix >= P1) return;
    const int h = pix / W;
    const int w = pix - h * W;
    const int oc0 = g * CG;

    // load q for this pixel's group
    float qreg[CG];
    const float* qp = q + ((size_t)b * OUTC + oc0) * P1 + pix;
    #pragma unroll
    for (int c = 0; c < CG; ++c) qreg[c] = qp[(size_t)c * P1];

    // bias dot: groups 0..3 -> rel_h (depends on tap row i), 4..7 -> rel_w (tap col j)
    const float* rel = (g < 4) ? (rel_h + oc0 * KS) : (rel_w + (oc0 - 128) * KS);
    float biasdot[KS];
    #pragma unroll
    for (int t = 0; t < KS; ++t) {
        float s = 0.f;
        #pragma unroll
        for (int c = 0; c < CG; ++c) s += qreg[c] * rel[c * KS + t];
        biasdot[t] = s;
    }

    float logits[KS * KS];
    #pragma unroll
    for (int i = 0; i < KS; ++i)
        #pragma unroll
        for (int j = 0; j < KS; ++j)
            logits[i * KS + j] = (g < 4) ? biasdot[i] : biasdot[j];

    const float* kp = kk + ((size_t)b * OUTC + oc0) * P2 + (h * WP + w);
    #pragma unroll 4
    for (int c = 0; c < CG; ++c) {
        const float* kc = kp + (size_t)c * P2;
        const float qc = qreg[c];
        #pragma unroll
        for (int i = 0; i < KS; ++i)
            #pragma unroll
            for (int j = 0; j < KS; ++j)
                logits[i * KS + j] += qc * kc[i * WP + j];
    }

    // softmax over 49 taps
    float m = logits[0];
    #pragma unroll
    for (int t = 1; t < KS * KS; ++t) m = fmaxf(m, logits[t]);
    float sum = 0.f;
    #pragma unroll
    for (int t = 0; t < KS * KS; ++t) {
        const float e = __expf(logits[t] - m);
        logits[t] = e;
        sum += e;
    }
    const float inv = 1.f / sum;

    const float* vp = vv + ((size_t)b * OUTC + oc0) * P2 + (h * WP + w);
    float* op = out + ((size_t)b * OUTC + oc0) * P1 + pix;
    #pragma unroll 4
    for (int c = 0; c < CG; ++c) {
        const float* vc = vp + (size_t)c * P2;
        float s = 0.f;
        #pragma unroll
        for (int i = 0; i < KS; ++i)
            #pragma unroll
            for (int j = 0; j < KS; ++j)
                s += logits[i * KS + j] * vc[i * WP + j];
        op[(size_t)c * P1] = s * inv;
    }
}

extern "C" void kernel_launch(void* const* d_in, const int* in_sizes, int n_in,
                              void* d_out, int out_size, void* d_ws, size_t ws_size,
                              hipStream_t stream) {
    const float* fm = (const float*)d_in[0];
    const float* wq = (const float*)d_in[1];
    const float* wk = (const float*)d_in[2];
    const float* wv = (const float*)d_in[3];
    const float* rh = (const float*)d_in[4];
    const float* rw = (const float*)d_in[5];
    float* out = (float*)d_out;

    float* ws = (float*)d_ws;
    float* q  = ws;                                    // B*OUTC*P1 = 1,605,632 floats
    float* kk = q + (size_t)B * OUTC * P1;             // B*OUTC*P2 = 1,968,128 floats
    float* vv = kk + (size_t)B * OUTC * P2;            // B*OUTC*P2

    proj_q_kernel<<<dim3(P1 / TP, OUTC / TO, B), 256, 0, stream>>>(fm, wq, q);
    proj_kv_kernel<<<dim3((P2 + TP - 1) / TP, OUTC / TO, B), 256, 0, stream>>>(fm, wk, wv, kk, vv);
    attn_kernel<<<dim3((P1 + 255) / 256, G, B), 256, 0, stream>>>(q, kk, vv, rh, rw, out);
}

// Round 2
// 161.065 us; speedup vs baseline: 1.5440x; 1.5440x over previous
//
#include <hip/hip_runtime.h>
#include <hip/hip_bf16.h>

// Problem constants
#define B    2
#define CIN  256
#define H    56
#define W    56
#define OUTC 256
#define KS   7
#define PAD  3
#define G    8
#define CG   32
#define HP   62           // H + 2*PAD
#define WP   62
#define P1   (H * W)      // 3136
#define P2   (HP * WP)    // 3844

// GEMM tile
#define TO 64
#define TP 64
#define TK 16

// ---------------------------------------------------------------------------
// q[b,o,p] = sum_c w_q[o,c] * fm[b, CIN + c, p]
// 64x64 tile, 256 thr, per-thread 4x4 with CONSECUTIVE o and p -> b128 LDS.
// ---------------------------------------------------------------------------
__global__ __launch_bounds__(256) void proj_q_kernel(const float* __restrict__ fm,
                                                     const float* __restrict__ wq,
                                                     float* __restrict__ q) {
    __shared__ float  sW[TK][TO];          // [k][o]
    __shared__ float4 sX[TK][TP / 4];      // [k][p/4]
    const int b  = blockIdx.z;
    const int o0 = blockIdx.y * TO;
    const int p0 = blockIdx.x * TP;
    const float* X = fm + ((size_t)b * (2 * CIN) + CIN) * P1;   // fm_t1[b]
    const int tid = threadIdx.x;
    const int tx = tid & 15;      // p-group (4 consecutive p)
    const int ty = tid >> 4;      // o-group (4 consecutive o)

    // staging maps (fixed over k loop)
    const int wo = tid >> 2;            // 0..63  : o for W staging
    const int wk4 = (tid & 3) * 4;      // 0,4,8,12: k base for W staging (float4 over c)
    const int xk = tid >> 4;            // 0..15  : k for X staging
    const int xp4 = (tid & 15) * 4;     // p base for X staging

    float acc[4][4] = {};
    for (int k0 = 0; k0 < CIN; k0 += TK) {
        { // W tile: float4 over c (coalesced), scatter into sW rows
            const float4 wv = *(const float4*)&wq[(size_t)(o0 + wo) * CIN + k0 + wk4];
            sW[wk4 + 0][wo] = wv.x;
            sW[wk4 + 1][wo] = wv.y;
            sW[wk4 + 2][wo] = wv.z;
            sW[wk4 + 3][wo] = wv.w;
        }
        { // X tile: float4 load + b128 LDS write
            sX[xk][tid & 15] = *(const float4*)&X[(size_t)(k0 + xk) * P1 + p0 + xp4];
        }
        __syncthreads();
        #pragma unroll
        for (int k = 0; k < TK; ++k) {
            const float4 xv = sX[k][tx];
            const float4 wv = *(const float4*)&sW[k][ty * 4];
            const float xs[4] = {xv.x, xv.y, xv.z, xv.w};
            const float wsr[4] = {wv.x, wv.y, wv.z, wv.w};
            #pragma unroll
            for (int aa = 0; aa < 4; ++aa)
                #pragma unroll
                for (int bb = 0; bb < 4; ++bb)
                    acc[aa][bb] += wsr[aa] * xs[bb];
        }
        __syncthreads();
    }
    float* qb = q + (size_t)b * OUTC * P1;
    #pragma unroll
    for (int aa = 0; aa < 4; ++aa) {
        float4 ov = make_float4(acc[aa][0], acc[aa][1], acc[aa][2], acc[aa][3]);
        *(float4*)&qb[(size_t)(o0 + ty * 4 + aa) * P1 + p0 + tx * 4] = ov;
    }
}

// ---------------------------------------------------------------------------
// kk/vv[b,o,pp] = w_{k,v} x padded(fm_t0)   (pp over 62*62, shared X tile)
// ---------------------------------------------------------------------------
__global__ __launch_bounds__(256) void proj_kv_kernel(const float* __restrict__ fm,
                                                      const float* __restrict__ wk,
                                                      const float* __restrict__ wv,
                                                      float* __restrict__ kk,
                                                      float* __restrict__ vv) {
    __shared__ float  sWk[TK][TO];
    __shared__ float  sWv[TK][TO];
    __shared__ float4 sX[TK][TP / 4];
    const int b  = blockIdx.z;
    const int o0 = blockIdx.y * TO;
    const int p0 = blockIdx.x * TP;
    const float* X = fm + (size_t)b * (2 * CIN) * P1;   // fm_t0[b]
    const int tid = threadIdx.x;
    const int tx = tid & 15;
    const int ty = tid >> 4;

    const int wo = tid >> 2;
    const int wk4 = (tid & 3) * 4;
    const int xk = tid >> 4;
    const int xp4 = (tid & 15) * 4;

    // padded-pixel -> source offsets (fixed over k loop)
    int so[4];
    #pragma unroll
    for (int j = 0; j < 4; ++j) {
        const int pl = p0 + xp4 + j;
        so[j] = -1;
        if (pl < P2) {
            const int y = pl / WP, x = pl - y * WP;
            const int iy = y - PAD, ix = x - PAD;
            if (iy >= 0 && iy < H && ix >= 0 && ix < W) so[j] = iy * W + ix;
        }
    }

    float acck[4][4] = {};
    float accv[4][4] = {};
    for (int k0 = 0; k0 < CIN; k0 += TK) {
        {
            const float4 wkv = *(const float4*)&wk[(size_t)(o0 + wo) * CIN + k0 + wk4];
            const float4 wvv = *(const float4*)&wv[(size_t)(o0 + wo) * CIN + k0 + wk4];
            sWk[wk4 + 0][wo] = wkv.x; sWk[wk4 + 1][wo] = wkv.y;
            sWk[wk4 + 2][wo] = wkv.z; sWk[wk4 + 3][wo] = wkv.w;
            sWv[wk4 + 0][wo] = wvv.x; sWv[wk4 + 1][wo] = wvv.y;
            sWv[wk4 + 2][wo] = wvv.z; sWv[wk4 + 3][wo] = wvv.w;
        }
        {
            const float* Xk = X + (size_t)(k0 + xk) * P1;
            float4 xv;
            xv.x = (so[0] >= 0) ? Xk[so[0]] : 0.f;
            xv.y = (so[1] >= 0) ? Xk[so[1]] : 0.f;
            xv.z = (so[2] >= 0) ? Xk[so[2]] : 0.f;
            xv.w = (so[3] >= 0) ? Xk[so[3]] : 0.f;
            sX[xk][tid & 15] = xv;
        }
        __syncthreads();
        #pragma unroll
        for (int k = 0; k < TK; ++k) {
            const float4 xv = sX[k][tx];
            const float4 wka = *(const float4*)&sWk[k][ty * 4];
            const float4 wva = *(const float4*)&sWv[k][ty * 4];
            const float xs[4]  = {xv.x, xv.y, xv.z, xv.w};
            const float wks[4] = {wka.x, wka.y, wka.z, wka.w};
            const float wvs[4] = {wva.x, wva.y, wva.z, wva.w};
            #pragma unroll
            for (int aa = 0; aa < 4; ++aa)
                #pragma unroll
                for (int bb = 0; bb < 4; ++bb) {
                    acck[aa][bb] += wks[aa] * xs[bb];
                    accv[aa][bb] += wvs[aa] * xs[bb];
                }
        }
        __syncthreads();
    }
    float* kb = kk + (size_t)b * OUTC * P2;
    float* vb = vv + (size_t)b * OUTC * P2;
    const int p = p0 + tx * 4;
    if (p < P2) {
        #pragma unroll
        for (int aa = 0; aa < 4; ++aa) {
            const size_t row = (size_t)(o0 + ty * 4 + aa);
            *(float4*)&kb[row * P2 + p] = make_float4(acck[aa][0], acck[aa][1], acck[aa][2], acck[aa][3]);
            *(float4*)&vb[row * P2 + p] = make_float4(accv[aa][0], accv[aa][1], accv[aa][2], accv[aa][3]);
        }
    }
}

// ---------------------------------------------------------------------------
// Grouped 7x7 attention, LDS-staged.
// Block = 2 pixel rows x 56 cols for one (b,g): 128 threads, 112 active.
// Window = 8 padded rows x 62 cols = 496 positions (contiguous per channel!).
// LDS layout: float4 sbuf[sub 0..7][pos 0..495] holding channels sub*4..+3.
// ---------------------------------------------------------------------------
#define NPOS 496   // 8 * 62
__global__ __launch_bounds__(128) void attn_kernel(const float* __restrict__ q,
                                                   const float* __restrict__ kk,
                                                   const float* __restrict__ vv,
                                                   const float* __restrict__ rel_h,
                                                   const float* __restrict__ rel_w,
                                                   float* __restrict__ out) {
    __shared__ float4 sbuf[8 * NPOS];   // 63,488 B

    const int b  = blockIdx.z;
    const int g  = blockIdx.y;
    const int r0 = blockIdx.x * 2;      // first pixel row of strip
    const int oc0 = g * CG;
    const size_t boc = (size_t)b * OUTC + oc0;
    const int tid = threadIdx.x;
    const bool active = tid < 112;
    const int rr = tid / 56;            // 0..1 row in strip
    const int cx = tid - rr * 56;       // 0..55 col
    const int pix = (r0 + rr) * W + cx;

    // ---- stage kk window: 8 subs x 496 pos, float4 over channels ----
    {
        const size_t base = boc * P2 + r0 * WP;
        #pragma unroll 1
        for (int it = 0; it < 31; ++it) {
            const int idx = tid + it * 128;        // 0..3967
            const int sub = idx / NPOS;
            const int pos = idx - sub * NPOS;
            const float* g0 = kk + base + (size_t)(sub * 4) * P2 + pos;
            sbuf[idx] = make_float4(g0[0], g0[(size_t)P2], g0[(size_t)2 * P2], g0[(size_t)3 * P2]);
        }
    }
    __syncthreads();

    float logits[KS * KS];
    float q4x[8], q4y[8], q4z[8], q4w[8];
    if (active) {
        // q for this pixel (32 channels as 8 float4 components)
        #pragma unroll
        for (int sub = 0; sub < 8; ++sub) {
            const float* qp = q + (boc + sub * 4) * P1 + pix;
            q4x[sub] = qp[0];
            q4y[sub] = qp[(size_t)P1];
            q4z[sub] = qp[(size_t)2 * P1];
            q4w[sub] = qp[(size_t)3 * P1];
        }
        // bias dot: logits bias = sum_c q[c]*bias[c][tap]; groups 0..3 use rel_h (row i),
        // groups 4..7 use rel_w (col j)
        const float* rel = (g < 4) ? (rel_h + oc0 * KS) : (rel_w + (oc0 - 128) * KS);
        float biasdot[KS];
        #pragma unroll
        for (int t = 0; t < KS; ++t) {
            float s = 0.f;
            #pragma unroll
            for (int sub = 0; sub < 8; ++sub) {
                s += q4x[sub] * rel[(sub * 4 + 0) * KS + t];
                s += q4y[sub] * rel[(sub * 4 + 1) * KS + t];
                s += q4z[sub] * rel[(sub * 4 + 2) * KS + t];
                s += q4w[sub] * rel[(sub * 4 + 3) * KS + t];
            }
            biasdot[t] = s;
        }
        #pragma unroll
        for (int i = 0; i < KS; ++i)
            #pragma unroll
            for (int j = 0; j < KS; ++j)
                logits[i * KS + j] = (g < 4) ? biasdot[i] : biasdot[j];

        // logits += q . k  over 32 channels via b128 LDS reads
        #pragma unroll
        for (int sub = 0; sub < 8; ++sub) {
            const float qx = q4x[sub], qy = q4y[sub], qz = q4z[sub], qw = q4w[sub];
            #pragma unroll
            for (int i = 0; i < KS; ++i) {
                const int rowoff = sub * NPOS + (rr + i) * WP + cx;
                #pragma unroll
                for (int j = 0; j < KS; ++j) {
                    const float4 kv = sbuf[rowoff + j];
                    logits[i * KS + j] += qx * kv.x + qy * kv.y + qz * kv.z + qw * kv.w;
                }
            }
        }

        // softmax over 49 taps (weights left unnormalized; fold 1/sum at the end)
        float m = logits[0];
        #pragma unroll
        for (int t = 1; t < KS * KS; ++t) m = fmaxf(m, logits[t]);
        float sum = 0.f;
        #pragma unroll
        for (int t = 0; t < KS * KS; ++t) {
            const float e = __expf(logits[t] - m);
            logits[t] = e;
            sum += e;
        }
        const float inv = 1.f / sum;
        #pragma unroll
        for (int t = 0; t < KS * KS; ++t) logits[t] *= inv;
    }
    __syncthreads();

    // ---- stage vv window over the same buffer ----
    {
        const size_t base = boc * P2 + r0 * WP;
        #pragma unroll 1
        for (int it = 0; it < 31; ++it) {
            const int idx = tid + it * 128;
            const int sub = idx / NPOS;
            const int pos = idx - sub * NPOS;
            const float* g0 = vv + base + (size_t)(sub * 4) * P2 + pos;
            sbuf[idx] = make_float4(g0[0], g0[(size_t)P2], g0[(size_t)2 * P2], g0[(size_t)3 * P2]);
        }
    }
    __syncthreads();

    if (active) {
        #pragma unroll
        for (int sub = 0; sub < 8; ++sub) {
            float ax = 0.f, ay = 0.f, az = 0.f, aw = 0.f;
            #pragma unroll
            for (int i = 0; i < KS; ++i) {
                const int rowoff = sub * NPOS + (rr + i) * WP + cx;
                #pragma unroll
                for (int j = 0; j < KS; ++j) {
                    const float4 v4 = sbuf[rowoff + j];
                    const float wt = logits[i * KS + j];
                    ax += wt * v4.x; ay += wt * v4.y; az += wt * v4.z; aw += wt * v4.w;
                }
            }
            float* op = out + (boc + sub * 4) * P1 + pix;
            op[0] = ax;
            op[(size_t)P1] = ay;
            op[(size_t)2 * P1] = az;
            op[(size_t)3 * P1] = aw;
        }
    }
}

extern "C" void kernel_launch(void* const* d_in, const int* in_sizes, int n_in,
                              void* d_out, int out_size, void* d_ws, size_t ws_size,
                              hipStream_t stream) {
    const float* fm = (const float*)d_in[0];
    const float* wq = (const float*)d_in[1];
    const float* wk = (const float*)d_in[2];
    const float* wv = (const float*)d_in[3];
    const float* rh = (const float*)d_in[4];
    const float* rw = (const float*)d_in[5];
    float* out = (float*)d_out;

    float* ws = (float*)d_ws;
    float* q  = ws;                                    // B*OUTC*P1 floats
    float* kk = q + (size_t)B * OUTC * P1;             // B*OUTC*P2 floats
    float* vv = kk + (size_t)B * OUTC * P2;            // B*OUTC*P2 floats

    proj_q_kernel<<<dim3(P1 / TP, OUTC / TO, B), 256, 0, stream>>>(fm, wq, q);
    proj_kv_kernel<<<dim3((P2 + TP - 1) / TP, OUTC / TO, B), 256, 0, stream>>>(fm, wk, wv, kk, vv);
    attn_kernel<<<dim3(H / 2, G, B), 128, 0, stream>>>(q, kk, vv, rh, rw, out);
}

// Round 3
// 146.648 us; speedup vs baseline: 1.6958x; 1.0983x over previous
//
#include <hip/hip_runtime.h>
#include <hip/hip_bf16.h>

// Problem constants
#define B    2
#define CIN  256
#define H    56
#define W    56
#define OUTC 256
#define KS   7
#define PAD  3
#define G    8
#define CG   32
#define HP   62           // H + 2*PAD
#define WP   62
#define P1   (H * W)      // 3136
#define P2   (HP * WP)    // 3844

// GEMM tile
#define TO 64
#define TP 64
#define TK 16

// ---------------------------------------------------------------------------
// q[b,o,p] = sum_c w_q[o,c] * fm[b, CIN + c, p]
// 64x64 tile, 256 thr, per-thread 4x4, software-prefetched staging.
// ---------------------------------------------------------------------------
__global__ __launch_bounds__(256) void proj_q_kernel(const float* __restrict__ fm,
                                                     const float* __restrict__ wq,
                                                     float* __restrict__ q) {
    __shared__ float  sW[TK][TO];          // [k][o]
    __shared__ float4 sX[TK][TP / 4];      // [k][p/4]
    const int b  = blockIdx.z;
    const int o0 = blockIdx.y * TO;
    const int p0 = blockIdx.x * TP;
    const float* X = fm + ((size_t)b * (2 * CIN) + CIN) * P1;   // fm_t1[b]
    const int tid = threadIdx.x;
    const int tx = tid & 15;      // p-group (4 consecutive p)
    const int ty = tid >> 4;      // o-group (4 consecutive o)

    const int wo  = tid >> 2;           // 0..63  : o for W staging
    const int wk4 = (tid & 3) * 4;      // k base for W staging
    const int xk  = tid >> 4;           // 0..15  : k for X staging
    const int xp4 = (tid & 15) * 4;     // p base for X staging

    const float* wptr = wq + (size_t)(o0 + wo) * CIN + wk4;
    const float* xptr = X + (size_t)xk * P1 + p0 + xp4;

    float4 wv = *(const float4*)wptr;
    float4 xv = *(const float4*)xptr;

    float acc[4][4] = {};
    for (int k0 = 0; k0 < CIN; k0 += TK) {
        sW[wk4 + 0][wo] = wv.x;
        sW[wk4 + 1][wo] = wv.y;
        sW[wk4 + 2][wo] = wv.z;
        sW[wk4 + 3][wo] = wv.w;
        sX[xk][tid & 15] = xv;
        __syncthreads();
        if (k0 + TK < CIN) {   // prefetch next tile; drains during FMA loop
            wv = *(const float4*)(wptr + (k0 + TK));
            xv = *(const float4*)(xptr + (size_t)(k0 + TK) * P1);
        }
        #pragma unroll
        for (int k = 0; k < TK; ++k) {
            const float4 x4 = sX[k][tx];
            const float4 w4 = *(const float4*)&sW[k][ty * 4];
            const float xs[4]  = {x4.x, x4.y, x4.z, x4.w};
            const float wsr[4] = {w4.x, w4.y, w4.z, w4.w};
            #pragma unroll
            for (int aa = 0; aa < 4; ++aa)
                #pragma unroll
                for (int bb = 0; bb < 4; ++bb)
                    acc[aa][bb] += wsr[aa] * xs[bb];
        }
        __syncthreads();
    }
    float* qb = q + (size_t)b * OUTC * P1;
    #pragma unroll
    for (int aa = 0; aa < 4; ++aa)
        *(float4*)&qb[(size_t)(o0 + ty * 4 + aa) * P1 + p0 + tx * 4] =
            make_float4(acc[aa][0], acc[aa][1], acc[aa][2], acc[aa][3]);
}

// ---------------------------------------------------------------------------
// kk/vv[b,o,pp] = w_{k,v} x padded(fm_t0)   (pp over 62*62, shared X tile)
// ---------------------------------------------------------------------------
__global__ __launch_bounds__(256) void proj_kv_kernel(const float* __restrict__ fm,
                                                      const float* __restrict__ wk,
                                                      const float* __restrict__ wv,
                                                      float* __restrict__ kk,
                                                      float* __restrict__ vv) {
    __shared__ float  sWk[TK][TO];
    __shared__ float  sWv[TK][TO];
    __shared__ float4 sX[TK][TP / 4];
    const int b  = blockIdx.z;
    const int o0 = blockIdx.y * TO;
    const int p0 = blockIdx.x * TP;
    const float* X = fm + (size_t)b * (2 * CIN) * P1;   // fm_t0[b]
    const int tid = threadIdx.x;
    const int tx = tid & 15;
    const int ty = tid >> 4;

    const int wo  = tid >> 2;
    const int wk4 = (tid & 3) * 4;
    const int xk  = tid >> 4;
    const int xp4 = (tid & 15) * 4;

    // padded-pixel -> source offsets (fixed over k loop)
    int so[4];
    #pragma unroll
    for (int j = 0; j < 4; ++j) {
        const int pl = p0 + xp4 + j;
        so[j] = -1;
        if (pl < P2) {
            const int y = pl / WP, x = pl - y * WP;
            const int iy = y - PAD, ix = x - PAD;
            if (iy >= 0 && iy < H && ix >= 0 && ix < W) so[j] = iy * W + ix;
        }
    }

    const float* wkp = wk + (size_t)(o0 + wo) * CIN + wk4;
    const float* wvp = wv + (size_t)(o0 + wo) * CIN + wk4;

    float4 wkr = *(const float4*)wkp;
    float4 wvr = *(const float4*)wvp;
    float4 xv;
    {
        const float* Xk = X + (size_t)xk * P1;
        xv.x = (so[0] >= 0) ? Xk[so[0]] : 0.f;
        xv.y = (so[1] >= 0) ? Xk[so[1]] : 0.f;
        xv.z = (so[2] >= 0) ? Xk[so[2]] : 0.f;
        xv.w = (so[3] >= 0) ? Xk[so[3]] : 0.f;
    }

    float acck[4][4] = {};
    float accv[4][4] = {};
    for (int k0 = 0; k0 < CIN; k0 += TK) {
        sWk[wk4 + 0][wo] = wkr.x; sWk[wk4 + 1][wo] = wkr.y;
        sWk[wk4 + 2][wo] = wkr.z; sWk[wk4 + 3][wo] = wkr.w;
        sWv[wk4 + 0][wo] = wvr.x; sWv[wk4 + 1][wo] = wvr.y;
        sWv[wk4 + 2][wo] = wvr.z; sWv[wk4 + 3][wo] = wvr.w;
        sX[xk][tid & 15] = xv;
        __syncthreads();
        if (k0 + TK < CIN) {   // prefetch next tile
            wkr = *(const float4*)(wkp + (k0 + TK));
            wvr = *(const float4*)(wvp + (k0 + TK));
            const float* Xk = X + (size_t)(k0 + TK + xk) * P1;
            xv.x = (so[0] >= 0) ? Xk[so[0]] : 0.f;
            xv.y = (so[1] >= 0) ? Xk[so[1]] : 0.f;
            xv.z = (so[2] >= 0) ? Xk[so[2]] : 0.f;
            xv.w = (so[3] >= 0) ? Xk[so[3]] : 0.f;
        }
        #pragma unroll
        for (int k = 0; k < TK; ++k) {
            const float4 x4  = sX[k][tx];
            const float4 wka = *(const float4*)&sWk[k][ty * 4];
            const float4 wva = *(const float4*)&sWv[k][ty * 4];
            const float xs[4]  = {x4.x, x4.y, x4.z, x4.w};
            const float wks[4] = {wka.x, wka.y, wka.z, wka.w};
            const float wvs[4] = {wva.x, wva.y, wva.z, wva.w};
            #pragma unroll
            for (int aa = 0; aa < 4; ++aa)
                #pragma unroll
                for (int bb = 0; bb < 4; ++bb) {
                    acck[aa][bb] += wks[aa] * xs[bb];
                    accv[aa][bb] += wvs[aa] * xs[bb];
                }
        }
        __syncthreads();
    }
    float* kb = kk + (size_t)b * OUTC * P2;
    float* vb = vv + (size_t)b * OUTC * P2;
    const int p = p0 + tx * 4;
    if (p < P2) {
        #pragma unroll
        for (int aa = 0; aa < 4; ++aa) {
            const size_t row = (size_t)(o0 + ty * 4 + aa);
            *(float4*)&kb[row * P2 + p] = make_float4(acck[aa][0], acck[aa][1], acck[aa][2], acck[aa][3]);
            *(float4*)&vb[row * P2 + p] = make_float4(accv[aa][0], accv[aa][1], accv[aa][2], accv[aa][3]);
        }
    }
}

// ---------------------------------------------------------------------------
// Grouped 7x7 attention, LDS-staged, pipelined staging.
// Block = 2 pixel rows x 56 cols for one (b,g): 128 threads, 112 active.
// Window = 8 padded rows x 62 cols = 496 positions (contiguous per channel).
// LDS: float4 sbuf[sub 0..7][pos 0..495] holding channels sub*4..sub*4+3.
// Staging map: sub = tid>>4, lane16 = tid&15; 31 iters of 16 pos each.
// All global loads use immediate offsets (it*64B) -> zero addr VALU, full MLP.
// ---------------------------------------------------------------------------
#define NPOS 496   // 8 * 62
__global__ __launch_bounds__(128, 1) void attn_kernel(const float* __restrict__ q,
                                                      const float* __restrict__ kk,
                                                      const float* __restrict__ vv,
                                                      const float* __restrict__ rel_h,
                                                      const float* __restrict__ rel_w,
                                                      float* __restrict__ out) {
    __shared__ float4 sbuf[8 * NPOS];   // 63,488 B -> 2 blocks/CU

    const int b  = blockIdx.z;
    const int g  = blockIdx.y;
    const int r0 = blockIdx.x * 2;      // first pixel row of strip
    const int oc0 = g * CG;
    const size_t boc = (size_t)b * OUTC + oc0;
    const int tid = threadIdx.x;
    const bool active = tid < 112;
    const int rr = tid / 56;            // 0..1 row in strip (active threads)
    const int cx = tid - rr * 56;       // 0..55 col
    const int pix = (r0 + rr) * W + cx;

    // staging geometry
    const int ssub   = tid >> 4;        // 0..7
    const int lane16 = tid & 15;        // 0..15
    const size_t wbase = boc * P2 + (size_t)r0 * WP + (size_t)(ssub * 4) * P2 + lane16;
    const float* k0p = kk + wbase;
    const float* v0p = vv + wbase;
    float4* sdst = &sbuf[ssub * NPOS + lane16];

    // q loads issued before staging barrier so they overlap k-window loads
    float q4x[8], q4y[8], q4z[8], q4w[8];
    if (active) {
        #pragma unroll
        for (int sub = 0; sub < 8; ++sub) {
            const float* qp = q + (boc + sub * 4) * P1 + pix;
            q4x[sub] = qp[0];
            q4y[sub] = qp[(size_t)P1];
            q4z[sub] = qp[(size_t)2 * P1];
            q4w[sub] = qp[(size_t)3 * P1];
        }
    }

    // ---- stage kk window (fully unrolled; immediate-offset loads) ----
    #pragma unroll
    for (int it = 0; it < 31; ++it) {
        sdst[it * 16] = make_float4(k0p[it * 16],
                                    k0p[it * 16 + (size_t)P2],
                                    k0p[it * 16 + (size_t)2 * P2],
                                    k0p[it * 16 + (size_t)3 * P2]);
    }
    __syncthreads();

    float logits[KS * KS];
    if (active) {
        // bias dot: groups 0..3 -> rel_h (tap row i), 4..7 -> rel_w (tap col j)
        const float* rel = (g < 4) ? (rel_h + oc0 * KS) : (rel_w + (oc0 - 128) * KS);
        float biasdot[KS];
        #pragma unroll
        for (int t = 0; t < KS; ++t) {
            float s = 0.f;
            #pragma unroll
            for (int sub = 0; sub < 8; ++sub) {
                s += q4x[sub] * rel[(sub * 4 + 0) * KS + t];
                s += q4y[sub] * rel[(sub * 4 + 1) * KS + t];
                s += q4z[sub] * rel[(sub * 4 + 2) * KS + t];
                s += q4w[sub] * rel[(sub * 4 + 3) * KS + t];
            }
            biasdot[t] = s;
        }
        #pragma unroll
        for (int i = 0; i < KS; ++i)
            #pragma unroll
            for (int j = 0; j < KS; ++j)
                logits[i * KS + j] = (g < 4) ? biasdot[i] : biasdot[j];

        // logits += q . k  (b128 LDS reads, 4 channels per read)
        #pragma unroll
        for (int sub = 0; sub < 8; ++sub) {
            const float qx = q4x[sub], qy = q4y[sub], qz = q4z[sub], qw = q4w[sub];
            #pragma unroll
            for (int i = 0; i < KS; ++i) {
                const int rowoff = sub * NPOS + (rr + i) * WP + cx;
                #pragma unroll
                for (int j = 0; j < KS; ++j) {
                    const float4 kv = sbuf[rowoff + j];
                    logits[i * KS + j] += qx * kv.x + qy * kv.y + qz * kv.z + qw * kv.w;
                }
            }
        }

        // softmax over 49 taps
        float m = logits[0];
        #pragma unroll
        for (int t = 1; t < KS * KS; ++t) m = fmaxf(m, logits[t]);
        float sum = 0.f;
        #pragma unroll
        for (int t = 0; t < KS * KS; ++t) {
            const float e = __expf(logits[t] - m);
            logits[t] = e;
            sum += e;
        }
        const float inv = 1.f / sum;
        #pragma unroll
        for (int t = 0; t < KS * KS; ++t) logits[t] *= inv;
    }
    __syncthreads();

    // ---- stage vv window over the same buffer ----
    #pragma unroll
    for (int it = 0; it < 31; ++it) {
        sdst[it * 16] = make_float4(v0p[it * 16],
                                    v0p[it * 16 + (size_t)P2],
                                    v0p[it * 16 + (size_t)2 * P2],
                                    v0p[it * 16 + (size_t)3 * P2]);
    }
    __syncthreads();

    if (active) {
        #pragma unroll
        for (int sub = 0; sub < 8; ++sub) {
            float ax = 0.f, ay = 0.f, az = 0.f, aw = 0.f;
            #pragma unroll
            for (int i = 0; i < KS; ++i) {
                const int rowoff = sub * NPOS + (rr + i) * WP + cx;
                #pragma unroll
                for (int j = 0; j < KS; ++j) {
                    const float4 v4 = sbuf[rowoff + j];
                    const float wt = logits[i * KS + j];
                    ax += wt * v4.x; ay += wt * v4.y; az += wt * v4.z; aw += wt * v4.w;
                }
            }
            float* op = out + (boc + sub * 4) * P1 + pix;
            op[0] = ax;
            op[(size_t)P1] = ay;
            op[(size_t)2 * P1] = az;
            op[(size_t)3 * P1] = aw;
        }
    }
}

extern "C" void kernel_launch(void* const* d_in, const int* in_sizes, int n_in,
                              void* d_out, int out_size, void* d_ws, size_t ws_size,
                              hipStream_t stream) {
    const float* fm = (const float*)d_in[0];
    const float* wq = (const float*)d_in[1];
    const float* wk = (const float*)d_in[2];
    const float* wv = (const float*)d_in[3];
    const float* rh = (const float*)d_in[4];
    const float* rw = (const float*)d_in[5];
    float* out = (float*)d_out;

    float* ws = (float*)d_ws;
    float* q  = ws;                                    // B*OUTC*P1 floats
    float* kk = q + (size_t)B * OUTC * P1;             // B*OUTC*P2 floats
    float* vv = kk + (size_t)B * OUTC * P2;            // B*OUTC*P2 floats

    proj_q_kernel<<<dim3(P1 / TP, OUTC / TO, B), 256, 0, stream>>>(fm, wq, q);
    proj_kv_kernel<<<dim3((P2 + TP - 1) / TP, OUTC / TO, B), 256, 0, stream>>>(fm, wk, wv, kk, vv);
    attn_kernel<<<dim3(H / 2, G, B), 128, 0, stream>>>(q, kk, vv, rh, rw, out);
}